// Round 1
// baseline (738.420 us; speedup 1.0000x reference)
//
#include <hip/hip_runtime.h>

#define BB 4
#define NN 4096
#define DD 256
#define PP 64
#define HH 1024
#define NCC 256
#define TOPK 8

// ---------------------------------------------------------------------------
// K1: Q = A@Wq+bq, K = A@Wk+bk, proj = A@Wc+bc, pn = proj/max(||proj||,1e-12)
// 16 rows/block, 256 threads.
// ---------------------------------------------------------------------------
__global__ __launch_bounds__(256) void k_proj(
    const float* __restrict__ act,
    const float* __restrict__ Wq, const float* __restrict__ bq,
    const float* __restrict__ Wk, const float* __restrict__ bk,
    const float* __restrict__ Wc, const float* __restrict__ bc,
    float* __restrict__ Qo, float* __restrict__ Ko, float* __restrict__ PNo)
{
    __shared__ float As[16][DD];   // 16KB
    __shared__ float Ps[16][PP];   // 4KB
    const int tid = threadIdx.x;
    const long row0 = (long)blockIdx.x * 16;

    {
        const float4* g4 = (const float4*)(act + row0 * DD);
        float4* s4 = (float4*)(&As[0][0]);
#pragma unroll
        for (int i = 0; i < 4; ++i) s4[tid + i * 256] = g4[tid + i * 256];
    }
    __syncthreads();

    const int col = tid & 63;
    const int rg  = tid >> 6;   // 0..3 -> rows rg*4+j
    float aq[4], ak[4], ac[4];
#pragma unroll
    for (int j = 0; j < 4; ++j) { aq[j] = bq[col]; ak[j] = bk[col]; ac[j] = bc[col]; }

    for (int d = 0; d < DD; ++d) {
        float wq = Wq[d * PP + col];
        float wk = Wk[d * PP + col];
        float wc = Wc[d * PP + col];
#pragma unroll
        for (int j = 0; j < 4; ++j) {
            float a = As[rg * 4 + j][d];
            aq[j] = fmaf(a, wq, aq[j]);
            ak[j] = fmaf(a, wk, ak[j]);
            ac[j] = fmaf(a, wc, ac[j]);
        }
    }
#pragma unroll
    for (int j = 0; j < 4; ++j) {
        long r = row0 + rg * 4 + j;
        Qo[r * PP + col] = aq[j];
        Ko[r * PP + col] = ak[j];
        Ps[rg * 4 + j][col] = ac[j];
    }
    __syncthreads();

    // norms: wave w handles rows 4w..4w+3, lane = column
    const int w = tid >> 6;
    const int lane = tid & 63;
#pragma unroll
    for (int j = 0; j < 4; ++j) {
        int r = w * 4 + j;
        float v = Ps[r][lane];
        float ss = v * v;
#pragma unroll
        for (int off = 32; off >= 1; off >>= 1) ss += __shfl_xor(ss, off, 64);
        float nrm = fmaxf(sqrtf(ss), 1e-12f);
        PNo[(row0 + r) * PP + lane] = v / nrm;
    }
}

// ---------------------------------------------------------------------------
// K2: scores = Q K^T / 8 -> per-row top-8 -> softmax -> incoming gather.
// 32 rows/block, 128-m LDS tiles, 4x4 register tiles. 256 threads.
// ---------------------------------------------------------------------------
__global__ __launch_bounds__(256) void k_topk(
    const float* __restrict__ Q, const float* __restrict__ K,
    const float* __restrict__ states, float* __restrict__ incoming)
{
    __shared__ float Qs[32][PP];                    // 8KB
    __shared__ union UU {
        float Ks[128][66];                          // 33.8KB (pad 66: 2-way only)
        struct MM { float cv[32][256]; unsigned short ci[32][256]; } m;  // 48KB
    } u;

    const int tid = threadIdx.x;
    const int b  = blockIdx.x >> 7;
    const int n0 = (blockIdx.x & 127) << 5;

    {
        const float4* g4 = (const float4*)(Q + ((long)b * NN + n0) * PP);
        float4* s4 = (float4*)(&Qs[0][0]);
        s4[tid] = g4[tid];
        s4[tid + 256] = g4[tid + 256];
    }

    const int mg = tid & 31;        // m sub-index
    const int rg = tid >> 5;        // 0..7 -> rows rg+8j
    float topv[4][TOPK];
    int   topi[4][TOPK];
    float vmin[4];
#pragma unroll
    for (int j = 0; j < 4; ++j) {
        vmin[j] = -1e30f;
#pragma unroll
        for (int t = 0; t < TOPK; ++t) { topv[j][t] = -1e30f; topi[j][t] = 0; }
    }

    for (int mt = 0; mt < NN / 128; ++mt) {
        const int m0 = mt << 7;
        __syncthreads();
        {
            const float2* g2 = (const float2*)(K + ((long)b * NN + m0) * PP);
#pragma unroll
            for (int t = 0; t < 16; ++t) {
                int q = tid + t * 256;                 // 0..4095 float2s
                *(float2*)(&u.Ks[q >> 5][(q & 31) << 1]) = g2[q];
            }
        }
        __syncthreads();

        float s[4][4];
#pragma unroll
        for (int j = 0; j < 4; ++j)
#pragma unroll
            for (int k = 0; k < 4; ++k) s[j][k] = 0.f;

#pragma unroll 4
        for (int p = 0; p < PP; ++p) {
            float qv[4], kv[4];
#pragma unroll
            for (int j = 0; j < 4; ++j) qv[j] = Qs[rg + 8 * j][p];
#pragma unroll
            for (int k = 0; k < 4; ++k) kv[k] = u.Ks[mg + 32 * k][p];
#pragma unroll
            for (int j = 0; j < 4; ++j)
#pragma unroll
                for (int k = 0; k < 4; ++k)
                    s[j][k] = fmaf(qv[j], kv[k], s[j][k]);
        }

#pragma unroll
        for (int j = 0; j < 4; ++j) {
#pragma unroll
            for (int k = 0; k < 4; ++k) {
                float val = s[j][k] * 0.125f;
                int idx = m0 + mg + 32 * k;
                if (val > vmin[j]) {
                    float mv = topv[j][0];
#pragma unroll
                    for (int t = 1; t < TOPK; ++t) mv = fminf(mv, topv[j][t]);
                    bool done = false;
#pragma unroll
                    for (int t = 0; t < TOPK; ++t) {   // static-index replace
                        bool take = (!done) && (topv[j][t] == mv);
                        if (take) { topv[j][t] = val; topi[j][t] = idx; done = true; }
                    }
                    float nm = topv[j][0];
#pragma unroll
                    for (int t = 1; t < TOPK; ++t) nm = fminf(nm, topv[j][t]);
                    vmin[j] = nm;
                }
            }
        }
    }
    __syncthreads();

    // dump per-thread candidates: row rr gets 32 threads x 8 = 256 candidates
#pragma unroll
    for (int j = 0; j < 4; ++j) {
        int rr = rg + 8 * j;
#pragma unroll
        for (int t = 0; t < TOPK; ++t) {
            u.m.cv[rr][mg * 8 + t] = topv[j][t];
            u.m.ci[rr][mg * 8 + t] = (unsigned short)topi[j][t];
        }
    }
    __syncthreads();

    // merge: wave w handles rows w*8 .. w*8+7
    const int w = tid >> 6;
    const int lane = tid & 63;
    for (int rr = w * 8; rr < w * 8 + 8; ++rr) {
        float v0 = u.m.cv[rr][lane];
        float v1 = u.m.cv[rr][lane + 64];
        float v2 = u.m.cv[rr][lane + 128];
        float v3 = u.m.cv[rr][lane + 192];
        float wv[8]; int wi[8];
#pragma unroll
        for (int e = 0; e < TOPK; ++e) {
            float lv = v0; int ls = 0;
            if (v1 > lv) { lv = v1; ls = 1; }
            if (v2 > lv) { lv = v2; ls = 2; }
            if (v3 > lv) { lv = v3; ls = 3; }
            int slot = ls * 64 + lane;
#pragma unroll
            for (int off = 32; off >= 1; off >>= 1) {
                float ov = __shfl_xor(lv, off, 64);
                int   os = __shfl_xor(slot, off, 64);
                if (ov > lv || (ov == lv && os < slot)) { lv = ov; slot = os; }
            }
            wv[e] = lv;
            wi[e] = (int)u.m.ci[rr][slot];
            if (slot == 0 * 64 + lane) v0 = -1e30f;
            if (slot == 1 * 64 + lane) v1 = -1e30f;
            if (slot == 2 * 64 + lane) v2 = -1e30f;
            if (slot == 3 * 64 + lane) v3 = -1e30f;
        }
        // softmax over the 8 (wv[0] is the max by construction)
        float mx = wv[0];
        float ex[8]; float Z = 0.f;
#pragma unroll
        for (int e = 0; e < TOPK; ++e) { ex[e] = expf(wv[e] - mx); Z += ex[e]; }
        float invZ = 1.0f / Z;

        float ax = 0.f, ay = 0.f, az = 0.f, aw = 0.f;
#pragma unroll
        for (int e = 0; e < TOPK; ++e) {
            const float4* sp = (const float4*)(states + ((long)b * NN + wi[e]) * DD);
            float4 sv = sp[lane];
            float we = ex[e] * invZ;
            ax = fmaf(we, sv.x, ax); ay = fmaf(we, sv.y, ay);
            az = fmaf(we, sv.z, az); aw = fmaf(we, sv.w, aw);
        }
        float4 o; o.x = ax; o.y = ay; o.z = az; o.w = aw;
        ((float4*)(incoming + ((long)b * NN + n0 + rr) * DD))[lane] = o;
    }
}

// ---------------------------------------------------------------------------
// K3: sim = pn pn^T; cmask = sim>0.7; combined; out = 0.8*inc + 0.2*combined
// ---------------------------------------------------------------------------
#define CAP 64
__global__ __launch_bounds__(256) void k_coal(
    const float* __restrict__ PN, const float* __restrict__ incoming,
    float* __restrict__ outs)
{
    __shared__ float Qs[32][PP];        // 8KB
    __shared__ float Ks[128][66];       // 33.8KB
    __shared__ int cnt[32];
    __shared__ unsigned short lst[32][CAP];   // 4KB

    const int tid = threadIdx.x;
    const int b  = blockIdx.x >> 7;
    const int n0 = (blockIdx.x & 127) << 5;

    if (tid < 32) cnt[tid] = 0;
    {
        const float4* g4 = (const float4*)(PN + ((long)b * NN + n0) * PP);
        float4* s4 = (float4*)(&Qs[0][0]);
        s4[tid] = g4[tid];
        s4[tid + 256] = g4[tid + 256];
    }

    const int mg = tid & 31;
    const int rg = tid >> 5;

    for (int mt = 0; mt < NN / 128; ++mt) {
        const int m0 = mt << 7;
        __syncthreads();
        {
            const float2* g2 = (const float2*)(PN + ((long)b * NN + m0) * PP);
#pragma unroll
            for (int t = 0; t < 16; ++t) {
                int q = tid + t * 256;
                *(float2*)(&Ks[q >> 5][(q & 31) << 1]) = g2[q];
            }
        }
        __syncthreads();

        float s[4][4];
#pragma unroll
        for (int j = 0; j < 4; ++j)
#pragma unroll
            for (int k = 0; k < 4; ++k) s[j][k] = 0.f;

#pragma unroll 4
        for (int p = 0; p < PP; ++p) {
            float qv[4], kv[4];
#pragma unroll
            for (int j = 0; j < 4; ++j) qv[j] = Qs[rg + 8 * j][p];
#pragma unroll
            for (int k = 0; k < 4; ++k) kv[k] = Ks[mg + 32 * k][p];
#pragma unroll
            for (int j = 0; j < 4; ++j)
#pragma unroll
                for (int k = 0; k < 4; ++k)
                    s[j][k] = fmaf(qv[j], kv[k], s[j][k]);
        }

#pragma unroll
        for (int j = 0; j < 4; ++j)
#pragma unroll
            for (int k = 0; k < 4; ++k) {
                if (s[j][k] > 0.7f) {
                    int pos = atomicAdd(&cnt[rg + 8 * j], 1);
                    if (pos < CAP) lst[rg + 8 * j][pos] = (unsigned short)(m0 + mg + 32 * k);
                }
            }
    }
    __syncthreads();

    const int w = tid >> 6;
    const int lane = tid & 63;
    for (int rr = w * 8; rr < w * 8 + 8; ++rr) {
        int c = cnt[rr];
        float inv = 1.0f / ((float)c + 1e-8f);
        int cc = (c < CAP) ? c : CAP;
        float ax = 0.f, ay = 0.f, az = 0.f, aw = 0.f;
        for (int i = 0; i < cc; ++i) {
            const float4* ip = (const float4*)(incoming + ((long)b * NN + lst[rr][i]) * DD);
            float4 v = ip[lane];
            ax += v.x; ay += v.y; az += v.z; aw += v.w;
        }
        const float4* self4 = (const float4*)(incoming + ((long)b * NN + n0 + rr) * DD);
        float4 sv = self4[lane];
        float4 o;
        o.x = 0.8f * sv.x + 0.2f * inv * ax;
        o.y = 0.8f * sv.y + 0.2f * inv * ay;
        o.z = 0.8f * sv.z + 0.2f * inv * az;
        o.w = 0.8f * sv.w + 0.2f * inv * aw;
        ((float4*)(outs + ((long)b * NN + n0 + rr) * DD))[lane] = o;
    }
}

// ---------------------------------------------------------------------------
// K4: hdc = tanh(3(out@Wh+bh)); bind; decay-write; cosine read.
// 16 rows/block, 8x8 register tile, 256 threads.
// ---------------------------------------------------------------------------
__global__ __launch_bounds__(256) void k_mem(
    const float* __restrict__ outs, const float* __restrict__ Wh,
    const float* __restrict__ bh, const float* __restrict__ keys,
    const float* __restrict__ pos_codes, const int* __restrict__ stepp,
    const float* __restrict__ mem,
    float* __restrict__ epi_out, float* __restrict__ sim_out)
{
    __shared__ float Ss[16][DD];    // 16KB
    __shared__ float Wt[8][HH];     // 32KB
    __shared__ float red[4][8][3];

    const int tid = threadIdx.x;
    const long row0 = (long)blockIdx.x * 16;

    {
        const float4* g4 = (const float4*)(outs + row0 * DD);
        float4* s4 = (float4*)(&Ss[0][0]);
#pragma unroll
        for (int i = 0; i < 4; ++i) s4[tid + i * 256] = g4[tid + i * 256];
    }

    const int hg = tid & 127;       // h = hg + 128k
    const int rg = tid >> 7;        // rows rg*8+j
    float acc[8][8];
#pragma unroll
    for (int j = 0; j < 8; ++j)
#pragma unroll
        for (int k = 0; k < 8; ++k) acc[j][k] = 0.f;

    for (int dt = 0; dt < DD / 8; ++dt) {
        __syncthreads();
        {
            const float4* g4 = (const float4*)(Wh + (long)dt * 8 * HH);
            float4* s4 = (float4*)(&Wt[0][0]);
#pragma unroll
            for (int t = 0; t < 8; ++t) s4[tid + t * 256] = g4[tid + t * 256];
        }
        __syncthreads();
#pragma unroll
        for (int dd = 0; dd < 8; ++dd) {
            float svv[8], wvv[8];
#pragma unroll
            for (int j = 0; j < 8; ++j) svv[j] = Ss[rg * 8 + j][dt * 8 + dd];
#pragma unroll
            for (int k = 0; k < 8; ++k) wvv[k] = Wt[dd][hg + 128 * k];
#pragma unroll
            for (int j = 0; j < 8; ++j)
#pragma unroll
                for (int k = 0; k < 8; ++k)
                    acc[j][k] = fmaf(svv[j], wvv[k], acc[j][k]);
        }
    }

    const int step = stepp[0];
    const int prow = ((step % NCC) + NCC) % NCC;
    float dnp[8], dnn[8], dpp[8];
#pragma unroll
    for (int j = 0; j < 8; ++j) { dnp[j] = 0.f; dnn[j] = 0.f; dpp[j] = 0.f; }

#pragma unroll
    for (int k = 0; k < 8; ++k) {
        int h = hg + 128 * k;
        float ps = pos_codes[(long)prow * HH + h];
        float bb = bh[h];
#pragma unroll
        for (int j = 0; j < 8; ++j) {
            long row = row0 + rg * 8 + j;
            int n = (int)(row & (NN - 1));
            float y = acc[j][k] + bb;
            float hd = tanhf(3.0f * y);
            float per = hd * keys[(long)n * HH + h];
            float bound = per * ps;
            float ne = 0.95f * mem[row * HH + h] + 0.05f * bound;
            epi_out[row * HH + h] = ne;
            dnp[j] = fmaf(ne, per, dnp[j]);
            dnn[j] = fmaf(ne, ne, dnn[j]);
            dpp[j] = fmaf(per, per, dpp[j]);
        }
    }

#pragma unroll
    for (int j = 0; j < 8; ++j) {
#pragma unroll
        for (int off = 32; off >= 1; off >>= 1) {
            dnp[j] += __shfl_xor(dnp[j], off, 64);
            dnn[j] += __shfl_xor(dnn[j], off, 64);
            dpp[j] += __shfl_xor(dpp[j], off, 64);
        }
    }
    const int w = tid >> 6;
    const int lane = tid & 63;
    if (lane == 0) {
#pragma unroll
        for (int j = 0; j < 8; ++j) {
            red[w][j][0] = dnp[j]; red[w][j][1] = dnn[j]; red[w][j][2] = dpp[j];
        }
    }
    __syncthreads();
    if (tid < 16) {
        int rgp = tid >> 3, j = tid & 7;
        float dot = red[rgp * 2][j][0] + red[rgp * 2 + 1][j][0];
        float nn  = red[rgp * 2][j][1] + red[rgp * 2 + 1][j][1];
        float pp  = red[rgp * 2][j][2] + red[rgp * 2 + 1][j][2];
        float na = fmaxf(sqrtf(nn), 1e-8f);
        float nb = fmaxf(sqrtf(pp), 1e-8f);
        sim_out[row0 + rgp * 8 + j] = dot / (na * nb);
    }
}

// ---------------------------------------------------------------------------
extern "C" void kernel_launch(void* const* d_in, const int* in_sizes, int n_in,
                              void* d_out, int out_size, void* d_ws, size_t ws_size,
                              hipStream_t stream)
{
    const float* states  = (const float*)d_in[0];
    const float* actions = (const float*)d_in[1];
    const float* mem     = (const float*)d_in[2];
    const float* Wq = (const float*)d_in[3];
    const float* bq = (const float*)d_in[4];
    const float* Wk = (const float*)d_in[5];
    const float* bk = (const float*)d_in[6];
    const float* Wc = (const float*)d_in[7];
    const float* bc = (const float*)d_in[8];
    const float* Wh = (const float*)d_in[9];
    const float* bh = (const float*)d_in[10];
    const float* keys = (const float*)d_in[11];
    const float* pos  = (const float*)d_in[12];
    const int*   step = (const int*)d_in[13];

    float* ws = (float*)d_ws;
    float* Q        = ws;                    // 1,048,576 floats
    float* K        = ws + 1048576;          // 1,048,576
    float* PN       = ws + 2097152;          // 1,048,576
    float* incoming = ws + 3145728;          // 4,194,304

    float* outs = (float*)d_out;                       // B*N*D
    float* epi  = outs + (long)BB * NN * DD;           // B*N*H
    float* simo = epi + (long)BB * NN * HH;            // B*N

    hipLaunchKernelGGL(k_proj, dim3(BB * NN / 16), dim3(256), 0, stream,
                       actions, Wq, bq, Wk, bk, Wc, bc, Q, K, PN);
    hipLaunchKernelGGL(k_topk, dim3(BB * (NN / 32)), dim3(256), 0, stream,
                       Q, K, states, incoming);
    hipLaunchKernelGGL(k_coal, dim3(BB * (NN / 32)), dim3(256), 0, stream,
                       PN, incoming, outs);
    hipLaunchKernelGGL(k_mem, dim3(BB * NN / 16), dim3(256), 0, stream,
                       outs, Wh, bh, keys, pos, step, mem, epi, simo);
}